// Round 1
// baseline (305.701 us; speedup 1.0000x reference)
//
#include <hip/hip_runtime.h>
#include <hip/hip_bf16.h>
#include <cstdint>

#define BB   2
#define SS   1024
#define HIDD 768
#define NH   12
#define DH   64
#define BH   (BB*NH)   // 24

typedef short bf16x8 __attribute__((ext_vector_type(8)));
typedef float f32x4  __attribute__((ext_vector_type(4)));

__device__ __forceinline__ unsigned short f2b(float x) {
    union { float f; uint32_t u; } v; v.f = x;
    uint32_t u = v.u;
    uint32_t r = (u + 0x7fffu + ((u >> 16) & 1u)) >> 16;
    return (unsigned short)r;
}

__device__ __forceinline__ void async16(const void* g, void* l) {
    __builtin_amdgcn_global_load_lds(
        (const __attribute__((address_space(1))) unsigned int*)g,
        (__attribute__((address_space(3))) unsigned int*)l,
        16, 0, 0);
}

// ---------------- kernel 1: hidden_states fp32 -> bf16 ----------------
__global__ void cvt_x(const float* __restrict__ x, unsigned short* __restrict__ xb) {
    int i = blockIdx.x * blockDim.x + threadIdx.x;   // one float4 per thread
    float4 v = ((const float4*)x)[i];
    ushort4 o;
    o.x = f2b(v.x); o.y = f2b(v.y); o.z = f2b(v.z); o.w = f2b(v.w);
    ((ushort4*)xb)[i] = o;
}

// ------------- kernel 2: W [k][n] fp32 -> Wt [n][k] bf16 (q|k|v) -------------
__global__ void transpose_w(const float* __restrict__ Wq, const float* __restrict__ Wk,
                            const float* __restrict__ Wv, unsigned short* __restrict__ Wt) {
    __shared__ float tile[32][33];
    const int w = blockIdx.z;
    const float* W = (w == 0) ? Wq : (w == 1) ? Wk : Wv;
    const int tx = threadIdx.x & 31, ty = threadIdx.x >> 5;   // 32 x 8
    const int k0 = blockIdx.x * 32, n0 = blockIdx.y * 32;
    for (int p = 0; p < 4; ++p)
        tile[ty + p * 8][tx] = W[(k0 + ty + p * 8) * HIDD + n0 + tx];
    __syncthreads();
    for (int p = 0; p < 4; ++p) {
        int n = n0 + ty + p * 8;
        Wt[(w * HIDD + n) * HIDD + k0 + tx] = f2b(tile[tx][ty + p * 8]);
    }
}

// ------------- kernel 3: QKV GEMM 2048x2304x768, bf16 MFMA -------------
// C[m][n] = X[m][k] * Wt[n][k]; epilogue adds bias, scales q by 1/8,
// scatters to Qh/Kh [bh][s][d] and VhT [bh][d][s] (all bf16).
__global__ __launch_bounds__(256) void qkv_gemm(
    const unsigned short* __restrict__ Xb, const unsigned short* __restrict__ Wt,
    const float* __restrict__ bq, const float* __restrict__ bk, const float* __restrict__ bv,
    unsigned short* __restrict__ Qh, unsigned short* __restrict__ Kh,
    unsigned short* __restrict__ VhT) {
    __shared__ __align__(16) unsigned short lA[128 * 32];
    __shared__ __align__(16) unsigned short lB[128 * 32];
    const int t = threadIdx.x;
    const int wave = t >> 6, lane = t & 63;
    const int l15 = lane & 15, quad = lane >> 4;
    const int m0 = blockIdx.x * 128;
    const int n0 = blockIdx.y * 128;
    const int wm = (wave >> 1) * 64, wn = (wave & 1) * 64;

    f32x4 acc[4][4] = {};

    for (int k0 = 0; k0 < HIDD; k0 += 32) {
        __syncthreads();   // protect LDS from previous iteration's reads
        for (int r = 0; r < 2; ++r) {
            int i = r * 256 + t;
            int ldsbase = (r * 256 + wave * 64) * 8;   // elems; dest = base + lane*16B
            async16(Xb + (m0 + (i >> 2)) * HIDD + k0 + (i & 3) * 8, &lA[ldsbase]);
            async16(Wt + (n0 + (i >> 2)) * HIDD + k0 + (i & 3) * 8, &lB[ldsbase]);
        }
        __syncthreads();   // drains vmcnt (global_load_lds) + barrier

        bf16x8 af[4], bf[4];
        #pragma unroll
        for (int i = 0; i < 4; ++i)
            af[i] = *(const bf16x8*)&lA[(wm + i * 16 + l15) * 32 + quad * 8];
        #pragma unroll
        for (int j = 0; j < 4; ++j)
            bf[j] = *(const bf16x8*)&lB[(wn + j * 16 + l15) * 32 + quad * 8];
        #pragma unroll
        for (int i = 0; i < 4; ++i)
            #pragma unroll
            for (int j = 0; j < 4; ++j)
                acc[i][j] = __builtin_amdgcn_mfma_f32_16x16x32_bf16(af[i], bf[j], acc[i][j], 0, 0, 0);
    }

    const int sect = (n0 >= 1536) ? 2 : (n0 >= 768) ? 1 : 0;   // uniform per block
    const float* bias = (sect == 0) ? bq : (sect == 1) ? bk : bv;
    #pragma unroll
    for (int i = 0; i < 4; ++i) {
        #pragma unroll
        for (int j = 0; j < 4; ++j) {
            int n  = n0 + wn + j * 16 + l15;
            int nn = n - sect * HIDD;
            int h = nn >> 6, d = nn & 63;
            float bval = bias[nn];
            #pragma unroll
            for (int r = 0; r < 4; ++r) {
                int m = m0 + wm + i * 16 + quad * 4 + r;   // C layout: row=quad*4+reg
                int b = m >> 10, s = m & 1023;
                float v = acc[i][j][r] + bval;
                if (sect == 0) {
                    Qh[((size_t)(b * NH + h) * SS + s) * DH + d] = f2b(v * 0.125f);
                } else if (sect == 1) {
                    Kh[((size_t)(b * NH + h) * SS + s) * DH + d] = f2b(v);
                } else {
                    VhT[((size_t)(b * NH + h) * DH + d) * SS + s] = f2b(v);
                }
            }
        }
    }
}

// ------------- kernel 4: flash attention with additive bias -------------
// grid: (S/64, BH). 4 waves/block, each wave owns 16 query rows.
__global__ __launch_bounds__(256) void flash_attn(
    const unsigned short* __restrict__ Qh, const unsigned short* __restrict__ Kh,
    const unsigned short* __restrict__ VhT,
    const float* __restrict__ rel, const float* __restrict__ rel2d,
    const float* __restrict__ amask, const float* __restrict__ hmask,
    float* __restrict__ out) {
    __shared__ __align__(16) unsigned short Plds[4][16 * 72];   // per-wave private, padded rows

    const int t = threadIdx.x;
    const int wave = t >> 6, lane = t & 63;
    const int l15 = lane & 15, quad = lane >> 4;
    const int bh = blockIdx.y;
    const int b = bh / NH, h = bh % NH;
    const int m0 = blockIdx.x * 64 + wave * 16;

    const unsigned short* Qp = Qh + (size_t)bh * SS * DH;
    const unsigned short* Kp = Kh + (size_t)bh * SS * DH;
    const unsigned short* Vp = VhT + (size_t)bh * DH * SS;
    const float* relp  = rel   + (size_t)bh * SS * SS;
    const float* rel2p = rel2d + (size_t)bh * SS * SS;
    const float* maskp = amask + (size_t)b * SS;

    bf16x8 qf0 = *(const bf16x8*)&Qp[(m0 + l15) * DH + quad * 8];
    bf16x8 qf1 = *(const bf16x8*)&Qp[(m0 + l15) * DH + 32 + quad * 8];

    f32x4 o[4] = {};
    float mrow[4] = {-1e30f, -1e30f, -1e30f, -1e30f};
    float lrow[4] = {0.f, 0.f, 0.f, 0.f};
    unsigned short* Pw = &Plds[wave][0];

    for (int j0 = 0; j0 < SS; j0 += 64) {
        // ---- scores: 16x64 = Q(16x64) . K^T ----
        f32x4 sc[4] = {};
        #pragma unroll
        for (int c = 0; c < 4; ++c) {
            bf16x8 k0f = *(const bf16x8*)&Kp[(j0 + c * 16 + l15) * DH + quad * 8];
            bf16x8 k1f = *(const bf16x8*)&Kp[(j0 + c * 16 + l15) * DH + 32 + quad * 8];
            sc[c] = __builtin_amdgcn_mfma_f32_16x16x32_bf16(qf0, k0f, sc[c], 0, 0, 0);
            sc[c] = __builtin_amdgcn_mfma_f32_16x16x32_bf16(qf1, k1f, sc[c], 0, 0, 0);
        }
        // ---- add (rel + rel2d)/8 + mask, in C layout ----
        float sv[4][4];
        #pragma unroll
        for (int c = 0; c < 4; ++c) {
            int col = j0 + c * 16 + l15;
            float mk = maskp[col];
            #pragma unroll
            for (int r = 0; r < 4; ++r) {
                size_t idx = (size_t)(m0 + quad * 4 + r) * SS + col;
                sv[c][r] = sc[c][r] + (relp[idx] + rel2p[idx]) * 0.125f + mk;
            }
        }
        // ---- online softmax per row (reg r <-> row quad*4+r) ----
        float alpha[4];
        #pragma unroll
        for (int r = 0; r < 4; ++r) {
            float mx = fmaxf(fmaxf(sv[0][r], sv[1][r]), fmaxf(sv[2][r], sv[3][r]));
            #pragma unroll
            for (int off = 1; off < 16; off <<= 1) mx = fmaxf(mx, __shfl_xor(mx, off, 64));
            float mnew = fmaxf(mrow[r], mx);
            alpha[r] = __expf(mrow[r] - mnew);
            mrow[r] = mnew;
            float rs = 0.f;
            #pragma unroll
            for (int c = 0; c < 4; ++c) {
                float p = __expf(sv[c][r] - mnew);
                sv[c][r] = p;
                rs += p;
            }
            #pragma unroll
            for (int off = 1; off < 16; off <<= 1) rs += __shfl_xor(rs, off, 64);
            lrow[r] = lrow[r] * alpha[r] + rs;
            o[0][r] *= alpha[r]; o[1][r] *= alpha[r]; o[2][r] *= alpha[r]; o[3][r] *= alpha[r];
        }
        // ---- P: C layout -> LDS [m][t] (A-operand layout), bf16 ----
        #pragma unroll
        for (int c = 0; c < 4; ++c)
            #pragma unroll
            for (int r = 0; r < 4; ++r)
                Pw[(quad * 4 + r) * 72 + c * 16 + l15] = f2b(sv[c][r]);

        bf16x8 pf0 = *(const bf16x8*)&Pw[l15 * 72 + quad * 8];
        bf16x8 pf1 = *(const bf16x8*)&Pw[l15 * 72 + 32 + quad * 8];
        // ---- O += P . V  (V^T gives contiguous-k B fragments) ----
        #pragma unroll
        for (int dt = 0; dt < 4; ++dt) {
            bf16x8 v0 = *(const bf16x8*)&Vp[(dt * 16 + l15) * SS + j0 + quad * 8];
            bf16x8 v1 = *(const bf16x8*)&Vp[(dt * 16 + l15) * SS + j0 + 32 + quad * 8];
            o[dt] = __builtin_amdgcn_mfma_f32_16x16x32_bf16(pf0, v0, o[dt], 0, 0, 0);
            o[dt] = __builtin_amdgcn_mfma_f32_16x16x32_bf16(pf1, v1, o[dt], 0, 0, 0);
        }
    }

    const float hm = hmask[h];
    #pragma unroll
    for (int r = 0; r < 4; ++r) {
        float inv = hm / lrow[r];
        int s = m0 + quad * 4 + r;
        float* op = out + ((size_t)(b * SS + s)) * HIDD + h * DH;
        #pragma unroll
        for (int dt = 0; dt < 4; ++dt) op[dt * 16 + l15] = o[dt][r] * inv;
    }
}

extern "C" void kernel_launch(void* const* d_in, const int* in_sizes, int n_in,
                              void* d_out, int out_size, void* d_ws, size_t ws_size,
                              hipStream_t stream) {
    const float* hs    = (const float*)d_in[0];
    const float* am    = (const float*)d_in[1];
    const float* hm    = (const float*)d_in[2];
    const float* rel   = (const float*)d_in[3];
    const float* rel2d = (const float*)d_in[4];
    const float* Wq    = (const float*)d_in[5];
    const float* bq    = (const float*)d_in[6];
    const float* Wk    = (const float*)d_in[7];
    const float* bk    = (const float*)d_in[8];
    const float* Wv    = (const float*)d_in[9];
    const float* bv    = (const float*)d_in[10];
    float* out = (float*)d_out;

    unsigned short* Xb  = (unsigned short*)d_ws;              // 2048*768
    unsigned short* Wt  = Xb + 2048 * HIDD;                   // 3*768*768
    unsigned short* Qh  = Wt + 3 * HIDD * HIDD;               // 24*1024*64 each
    unsigned short* Kh  = Qh + (size_t)BH * SS * DH;
    unsigned short* VhT = Kh + (size_t)BH * SS * DH;

    cvt_x<<<(2048 * HIDD / 4) / 256, 256, 0, stream>>>(hs, Xb);
    dim3 gT(24, 24, 3);
    transpose_w<<<gT, 256, 0, stream>>>(Wq, Wk, Wv, Wt);
    dim3 gG(16, 18);
    qkv_gemm<<<gG, 256, 0, stream>>>(Xb, Wt, bq, bk, bv, Qh, Kh, VhT);
    dim3 gF(16, BH);
    flash_attn<<<gF, 256, 0, stream>>>(Qh, Kh, VhT, rel, rel2d, am, hm, out);
}

// Round 2
// 287.149 us; speedup vs baseline: 1.0646x; 1.0646x over previous
//
#include <hip/hip_runtime.h>
#include <hip/hip_bf16.h>
#include <cstdint>

#define BB   2
#define SS   1024
#define HIDD 768
#define NH   12
#define DH   64
#define BH   (BB*NH)   // 24

typedef short bf16x8 __attribute__((ext_vector_type(8)));
typedef float f32x4  __attribute__((ext_vector_type(4)));

__device__ __forceinline__ unsigned short f2b(float x) {
    union { float f; uint32_t u; } v; v.f = x;
    uint32_t u = v.u;
    uint32_t r = (u + 0x7fffu + ((u >> 16) & 1u)) >> 16;
    return (unsigned short)r;
}

__device__ __forceinline__ void async16(const void* g, void* l) {
    __builtin_amdgcn_global_load_lds(
        (const __attribute__((address_space(1))) unsigned int*)g,
        (__attribute__((address_space(3))) unsigned int*)l,
        16, 0, 0);
}

// ---------------- kernel 1: hidden_states fp32 -> bf16 ----------------
__global__ void cvt_x(const float* __restrict__ x, unsigned short* __restrict__ xb) {
    int i = blockIdx.x * blockDim.x + threadIdx.x;   // one float4 per thread
    float4 v = ((const float4*)x)[i];
    ushort4 o;
    o.x = f2b(v.x); o.y = f2b(v.y); o.z = f2b(v.z); o.w = f2b(v.w);
    ((ushort4*)xb)[i] = o;
}

// ------------- kernel 2: W [k][n] fp32 -> Wt [n][k] bf16 (q|k|v) -------------
__global__ void transpose_w(const float* __restrict__ Wq, const float* __restrict__ Wk,
                            const float* __restrict__ Wv, unsigned short* __restrict__ Wt) {
    __shared__ float tile[32][33];
    const int w = blockIdx.z;
    const float* W = (w == 0) ? Wq : (w == 1) ? Wk : Wv;
    const int tx = threadIdx.x & 31, ty = threadIdx.x >> 5;   // 32 x 8
    const int k0 = blockIdx.x * 32, n0 = blockIdx.y * 32;
    for (int p = 0; p < 4; ++p)
        tile[ty + p * 8][tx] = W[(k0 + ty + p * 8) * HIDD + n0 + tx];
    __syncthreads();
    for (int p = 0; p < 4; ++p) {
        int n = n0 + ty + p * 8;
        Wt[(w * HIDD + n) * HIDD + k0 + tx] = f2b(tile[tx][ty + p * 8]);
    }
}

// ------------- kernel 3: QKV GEMM 2048x2304x768, bf16 MFMA -------------
// 64x128 tiles (576 blocks). C[m][n] = X[m][k] * Wt[n][k]; epilogue adds bias,
// scales q by 1/8, stores Qh/Kh/Vh all as [bh][s][d] bf16 (coalesced).
__global__ __launch_bounds__(256) void qkv_gemm(
    const unsigned short* __restrict__ Xb, const unsigned short* __restrict__ Wt,
    const float* __restrict__ bq, const float* __restrict__ bk, const float* __restrict__ bv,
    unsigned short* __restrict__ Qh, unsigned short* __restrict__ Kh,
    unsigned short* __restrict__ Vh) {
    __shared__ __align__(16) unsigned short lA[64 * 32];
    __shared__ __align__(16) unsigned short lB[128 * 32];
    const int t = threadIdx.x;
    const int wave = t >> 6, lane = t & 63;
    const int l15 = lane & 15, quad = lane >> 4;
    const int m0 = blockIdx.x * 64;
    const int n0 = blockIdx.y * 128;
    const int wm = (wave >> 1) * 32, wn = (wave & 1) * 64;

    f32x4 acc[2][4] = {};

    for (int k0 = 0; k0 < HIDD; k0 += 32) {
        __syncthreads();   // protect LDS from previous iteration's reads
        {
            // A: 64x32 = 256 chunks of 8 elems, one per thread
            int ldsA = (wave * 64) * 8;            // + lane*16B implicit
            async16(Xb + (m0 + (t >> 2)) * HIDD + k0 + (t & 3) * 8, &lA[ldsA]);
            // B: 128x32 = 512 chunks, two per thread
            for (int r = 0; r < 2; ++r) {
                int i = r * 256 + t;
                int ldsB = (r * 256 + wave * 64) * 8;
                async16(Wt + (n0 + (i >> 2)) * HIDD + k0 + (i & 3) * 8, &lB[ldsB]);
            }
        }
        __syncthreads();   // drains vmcnt (global_load_lds) + barrier

        bf16x8 af[2], bf[4];
        #pragma unroll
        for (int i = 0; i < 2; ++i)
            af[i] = *(const bf16x8*)&lA[(wm + i * 16 + l15) * 32 + quad * 8];
        #pragma unroll
        for (int j = 0; j < 4; ++j)
            bf[j] = *(const bf16x8*)&lB[(wn + j * 16 + l15) * 32 + quad * 8];
        #pragma unroll
        for (int i = 0; i < 2; ++i)
            #pragma unroll
            for (int j = 0; j < 4; ++j)
                acc[i][j] = __builtin_amdgcn_mfma_f32_16x16x32_bf16(af[i], bf[j], acc[i][j], 0, 0, 0);
    }

    const int sect = (n0 >= 1536) ? 2 : (n0 >= 768) ? 1 : 0;   // uniform per block
    const float* bias = (sect == 0) ? bq : (sect == 1) ? bk : bv;
    unsigned short* dst = (sect == 0) ? Qh : (sect == 1) ? Kh : Vh;
    const float scale = (sect == 0) ? 0.125f : 1.0f;
    #pragma unroll
    for (int i = 0; i < 2; ++i) {
        #pragma unroll
        for (int j = 0; j < 4; ++j) {
            int n  = n0 + wn + j * 16 + l15;
            int nn = n - sect * HIDD;
            int h = nn >> 6, d = nn & 63;
            float bval = bias[nn];
            #pragma unroll
            for (int r = 0; r < 4; ++r) {
                int m = m0 + wm + i * 16 + quad * 4 + r;   // C layout: row=quad*4+reg
                int b = m >> 10, s = m & 1023;
                float v = (acc[i][j][r] + bval) * scale;
                dst[((size_t)(b * NH + h) * SS + s) * DH + d] = f2b(v);
            }
        }
    }
}

// ------------- kernel 3b: Vh [bh][s][d] -> VhT [bh][d][s] -------------
__global__ __launch_bounds__(256) void transpose_v(
    const unsigned short* __restrict__ Vh, unsigned short* __restrict__ VhT) {
    __shared__ unsigned short tile[64][65];
    const int t = threadIdx.x;
    const int bh = blockIdx.y;
    const int s0 = blockIdx.x * 64;
    const int tx = t & 63, ty = t >> 6;   // 64 x 4
    const unsigned short* src = Vh + (size_t)bh * SS * DH;
    #pragma unroll
    for (int p = 0; p < 16; ++p)
        tile[ty + p * 4][tx] = src[(size_t)(s0 + ty + p * 4) * DH + tx];
    __syncthreads();
    unsigned short* dst = VhT + (size_t)bh * DH * SS;
    #pragma unroll
    for (int p = 0; p < 16; ++p)
        dst[(size_t)(ty + p * 4) * SS + s0 + tx] = tile[tx][ty + p * 4];
}

// ------------- kernel 4: flash attention with additive bias -------------
// grid: (S/16, BH). 4 waves/block; all waves share the same 16 query rows,
// each wave owns a disjoint 256-key range; block-level LDS combine at the end.
__global__ __launch_bounds__(256) void flash_attn(
    const unsigned short* __restrict__ Qh, const unsigned short* __restrict__ Kh,
    const unsigned short* __restrict__ VhT,
    const float* __restrict__ rel, const float* __restrict__ rel2d,
    const float* __restrict__ amask, const float* __restrict__ hmask,
    float* __restrict__ out) {
    __shared__ __align__(16) unsigned short Plds[4][16 * 72];   // per-wave private
    __shared__ float o_lds[4][16][64];
    __shared__ float m_lds[4][16];
    __shared__ float l_lds[4][16];

    const int t = threadIdx.x;
    const int wave = t >> 6, lane = t & 63;
    const int l15 = lane & 15, quad = lane >> 4;
    const int bh = blockIdx.y;
    const int b = bh / NH, h = bh % NH;
    const int m0 = blockIdx.x * 16;                 // 16 query rows, shared by waves

    const unsigned short* Qp = Qh + (size_t)bh * SS * DH;
    const unsigned short* Kp = Kh + (size_t)bh * SS * DH;
    const unsigned short* Vp = VhT + (size_t)bh * DH * SS;
    const float* relp  = rel   + (size_t)bh * SS * SS;
    const float* rel2p = rel2d + (size_t)bh * SS * SS;
    const float* maskp = amask + (size_t)b * SS;

    bf16x8 qf0 = *(const bf16x8*)&Qp[(m0 + l15) * DH + quad * 8];
    bf16x8 qf1 = *(const bf16x8*)&Qp[(m0 + l15) * DH + 32 + quad * 8];

    f32x4 o[4] = {};
    float mrow[4] = {-1e30f, -1e30f, -1e30f, -1e30f};
    float lrow[4] = {0.f, 0.f, 0.f, 0.f};
    unsigned short* Pw = &Plds[wave][0];

    const int jbeg = wave * 256, jend = jbeg + 256;
    for (int j0 = jbeg; j0 < jend; j0 += 64) {
        // ---- scores: 16x64 = Q(16x64) . K^T ----
        f32x4 sc[4] = {};
        #pragma unroll
        for (int c = 0; c < 4; ++c) {
            bf16x8 k0f = *(const bf16x8*)&Kp[(j0 + c * 16 + l15) * DH + quad * 8];
            bf16x8 k1f = *(const bf16x8*)&Kp[(j0 + c * 16 + l15) * DH + 32 + quad * 8];
            sc[c] = __builtin_amdgcn_mfma_f32_16x16x32_bf16(qf0, k0f, sc[c], 0, 0, 0);
            sc[c] = __builtin_amdgcn_mfma_f32_16x16x32_bf16(qf1, k1f, sc[c], 0, 0, 0);
        }
        // ---- add (rel + rel2d)/8 + mask, in C layout ----
        float sv[4][4];
        #pragma unroll
        for (int c = 0; c < 4; ++c) {
            int col = j0 + c * 16 + l15;
            float mk = maskp[col];
            #pragma unroll
            for (int r = 0; r < 4; ++r) {
                size_t idx = (size_t)(m0 + quad * 4 + r) * SS + col;
                sv[c][r] = sc[c][r] + (relp[idx] + rel2p[idx]) * 0.125f + mk;
            }
        }
        // ---- online softmax per row (reg r <-> row quad*4+r) ----
        float alpha[4];
        #pragma unroll
        for (int r = 0; r < 4; ++r) {
            float mx = fmaxf(fmaxf(sv[0][r], sv[1][r]), fmaxf(sv[2][r], sv[3][r]));
            #pragma unroll
            for (int off = 1; off < 16; off <<= 1) mx = fmaxf(mx, __shfl_xor(mx, off, 64));
            float mnew = fmaxf(mrow[r], mx);
            alpha[r] = __expf(mrow[r] - mnew);
            mrow[r] = mnew;
            float rs = 0.f;
            #pragma unroll
            for (int c = 0; c < 4; ++c) {
                float p = __expf(sv[c][r] - mnew);
                sv[c][r] = p;
                rs += p;
            }
            #pragma unroll
            for (int off = 1; off < 16; off <<= 1) rs += __shfl_xor(rs, off, 64);
            lrow[r] = lrow[r] * alpha[r] + rs;
            o[0][r] *= alpha[r]; o[1][r] *= alpha[r]; o[2][r] *= alpha[r]; o[3][r] *= alpha[r];
        }
        // ---- P: C layout -> LDS [m][t] (A-operand layout), bf16 ----
        #pragma unroll
        for (int c = 0; c < 4; ++c)
            #pragma unroll
            for (int r = 0; r < 4; ++r)
                Pw[(quad * 4 + r) * 72 + c * 16 + l15] = f2b(sv[c][r]);

        bf16x8 pf0 = *(const bf16x8*)&Pw[l15 * 72 + quad * 8];
        bf16x8 pf1 = *(const bf16x8*)&Pw[l15 * 72 + 32 + quad * 8];
        // ---- O += P . V  (V^T gives contiguous-k B fragments) ----
        #pragma unroll
        for (int dt = 0; dt < 4; ++dt) {
            bf16x8 v0 = *(const bf16x8*)&Vp[(dt * 16 + l15) * SS + j0 + quad * 8];
            bf16x8 v1 = *(const bf16x8*)&Vp[(dt * 16 + l15) * SS + j0 + 32 + quad * 8];
            o[dt] = __builtin_amdgcn_mfma_f32_16x16x32_bf16(pf0, v0, o[dt], 0, 0, 0);
            o[dt] = __builtin_amdgcn_mfma_f32_16x16x32_bf16(pf1, v1, o[dt], 0, 0, 0);
        }
    }

    // ---- block combine across the 4 key-range partials ----
    #pragma unroll
    for (int dt = 0; dt < 4; ++dt)
        #pragma unroll
        for (int r = 0; r < 4; ++r)
            o_lds[wave][quad * 4 + r][dt * 16 + l15] = o[dt][r];
    if (l15 == 0) {
        #pragma unroll
        for (int r = 0; r < 4; ++r) {
            m_lds[wave][quad * 4 + r] = mrow[r];
            l_lds[wave][quad * 4 + r] = lrow[r];
        }
    }
    __syncthreads();

    const float hm = hmask[h];
    const int col = t & 63, rsel = t >> 6;
    #pragma unroll
    for (int rr = 0; rr < 4; ++rr) {
        int row = rsel * 4 + rr;
        float m01 = fmaxf(m_lds[0][row], m_lds[1][row]);
        float m23 = fmaxf(m_lds[2][row], m_lds[3][row]);
        float mt = fmaxf(m01, m23);
        float lt = 0.f, val = 0.f;
        #pragma unroll
        for (int w = 0; w < 4; ++w) {
            float sc = __expf(m_lds[w][row] - mt);
            lt += sc * l_lds[w][row];
            val += sc * o_lds[w][row][col];
        }
        int s = m0 + row;
        out[((size_t)(b * SS + s)) * HIDD + h * DH + col] = val * hm / lt;
    }
}

extern "C" void kernel_launch(void* const* d_in, const int* in_sizes, int n_in,
                              void* d_out, int out_size, void* d_ws, size_t ws_size,
                              hipStream_t stream) {
    const float* hs    = (const float*)d_in[0];
    const float* am    = (const float*)d_in[1];
    const float* hm    = (const float*)d_in[2];
    const float* rel   = (const float*)d_in[3];
    const float* rel2d = (const float*)d_in[4];
    const float* Wq    = (const float*)d_in[5];
    const float* bq    = (const float*)d_in[6];
    const float* Wk    = (const float*)d_in[7];
    const float* bk    = (const float*)d_in[8];
    const float* Wv    = (const float*)d_in[9];
    const float* bv    = (const float*)d_in[10];
    float* out = (float*)d_out;

    unsigned short* Xb  = (unsigned short*)d_ws;              // 2048*768
    unsigned short* Wt  = Xb + 2048 * HIDD;                   // 3*768*768
    unsigned short* Qh  = Wt + 3 * HIDD * HIDD;               // 24*1024*64 each
    unsigned short* Kh  = Qh + (size_t)BH * SS * DH;
    unsigned short* Vh  = Kh + (size_t)BH * SS * DH;
    unsigned short* VhT = Vh + (size_t)BH * SS * DH;

    cvt_x<<<(2048 * HIDD / 4) / 256, 256, 0, stream>>>(hs, Xb);
    dim3 gT(24, 24, 3);
    transpose_w<<<gT, 256, 0, stream>>>(Wq, Wk, Wv, Wt);
    dim3 gG(32, 18);
    qkv_gemm<<<gG, 256, 0, stream>>>(Xb, Wt, bq, bk, bv, Qh, Kh, Vh);
    dim3 gV(16, BH);
    transpose_v<<<gV, 256, 0, stream>>>(Vh, VhT);
    dim3 gF(64, BH);
    flash_attn<<<gF, 256, 0, stream>>>(Qh, Kh, VhT, rel, rel2d, am, hm, out);
}